// Round 6
// baseline (264.325 us; speedup 1.0000x reference)
//
#include <hip/hip_runtime.h>

typedef __attribute__((ext_vector_type(8))) short short8;
typedef __attribute__((ext_vector_type(4))) float floatx4;

#define INVC 0.9995003746877732f
#define NCHUNK 33

__device__ __forceinline__ unsigned short f2bf(float f) {
    union { float f; unsigned int u; } c; c.f = f;
    unsigned int r = c.u + 0x7fffu + ((c.u >> 16) & 1u);
    return (unsigned short)(r >> 16);
}
__device__ __forceinline__ float bf2f(unsigned short u) {
    union { unsigned int u; float f; } c; c.u = ((unsigned int)u) << 16;
    return c.f;
}
__device__ __forceinline__ void gld_lds16(const unsigned short* g, unsigned short* l) {
    __builtin_amdgcn_global_load_lds(
        (const __attribute__((address_space(1))) unsigned int*)g,
        (__attribute__((address_space(3))) unsigned int*)l, 16, 0, 0);
}
// A/B-frag index: element (row in 16-row unit, k) -> offset; unit stride 512
__device__ __forceinline__ int fidx(int row, int k) {
    return (k >> 5) * 512 + (row + 16 * ((k >> 3) & 3)) * 8 + (k & 7);
}

// ---------------------------------------------------------------------------
// Prep: fp32->bf16 cast of pixel input + transpose-cast of 8 weight matrices
// ---------------------------------------------------------------------------
struct PrepPtrs {
    const float* src_pix;
    unsigned short* dst_pix;
    const float* W[8]; unsigned short* Wt[8];
};

__global__ __launch_bounds__(256) void prep_kernel(PrepPtrs P) {
    __shared__ float T[32][33];
    const int bid = blockIdx.x, t = threadIdx.x;
    if (bid < 4096) {
        int i = bid * 1024 + t * 4;
        float4 v = *(const float4*)(P.src_pix + i);
        unsigned long long pk = (unsigned long long)f2bf(v.x)
            | ((unsigned long long)f2bf(v.y) << 16)
            | ((unsigned long long)f2bf(v.z) << 32)
            | ((unsigned long long)f2bf(v.w) << 48);
        *(unsigned long long*)(P.dst_pix + i) = pk;
        return;
    }
    int rel = bid - 4096;
    const int KD[8]  = {128,128,256,256,256,256,128,2048};
    const int ND[8]  = {256,256,512,512,128,128,2048,128};
    const int CNT[8] = {32,32,128,128,32,32,256,256};
    int wi = 0;
    #pragma unroll
    for (int k = 0; k < 8; ++k) { if (rel >= CNT[k] && wi == k) { rel -= CNT[k]; wi = k + 1; } }
    const int K = KD[wi], N = ND[wi];
    const int ntn = N >> 5;
    const int tn = rel % ntn, tk = rel / ntn;
    const int n0 = tn * 32, k0 = tk * 32;
    const float* W = P.W[wi];
    unsigned short* Wt = P.Wt[wi];
    const int tx = t & 31, ty = t >> 5;
    #pragma unroll
    for (int i = 0; i < 4; ++i)
        T[ty + 8*i][tx] = W[(size_t)(k0 + ty + 8*i) * N + n0 + tx];
    __syncthreads();
    #pragma unroll
    for (int i = 0; i < 4; ++i)
        Wt[(size_t)(n0 + ty + 8*i) * K + k0 + tx] = f2bf(T[tx][ty + 8*i]);
}

// ---------------------------------------------------------------------------
// gemm device body: 128x128 tile, BK=32, 4 waves, fragment-ordered LDS
// ---------------------------------------------------------------------------
__device__ __forceinline__ void gemm_body(
    const unsigned short* __restrict__ A,
    const unsigned short* __restrict__ Bt,
    const float* __restrict__ bnp,
    const float* __restrict__ residF,
    unsigned short* __restrict__ outB,
    float* __restrict__ outF,
    int K, int Nc, int do_relu, int row0, int col0,
    unsigned short* As, unsigned short* Bs)
{
    const int t = threadIdx.x;
    const int lane = t & 63, w = t >> 6;
    const int l15 = lane & 15, quad = lane >> 4;
    const int wr = w >> 1, wc = w & 1;

    floatx4 acc[4][4];
    #pragma unroll
    for (int i = 0; i < 4; ++i)
        #pragma unroll
        for (int j = 0; j < 4; ++j) acc[i][j] = (floatx4){0.f, 0.f, 0.f, 0.f};

    const unsigned short* gA0 = A  + (size_t)(row0 + w*16     + l15) * K + quad*8;
    const unsigned short* gA1 = A  + (size_t)(row0 + (w+4)*16 + l15) * K + quad*8;
    const unsigned short* gB0 = Bt + (size_t)(col0 + w*16     + l15) * K + quad*8;
    const unsigned short* gB1 = Bt + (size_t)(col0 + (w+4)*16 + l15) * K + quad*8;
    unsigned short* lA0 = &As[w * 512];
    unsigned short* lA1 = &As[(w + 4) * 512];
    unsigned short* lB0 = &Bs[w * 512];
    unsigned short* lB1 = &Bs[(w + 4) * 512];

    for (int k0 = 0; k0 < K; k0 += 32) {
        __syncthreads();
        gld_lds16(gA0 + k0, lA0);
        gld_lds16(gA1 + k0, lA1);
        gld_lds16(gB0 + k0, lB0);
        gld_lds16(gB1 + k0, lB1);
        __syncthreads();
        short8 a[4], b[4];
        #pragma unroll
        for (int mt = 0; mt < 4; ++mt) a[mt] = *(const short8*)&As[(wr*4 + mt)*512 + lane*8];
        #pragma unroll
        for (int nt = 0; nt < 4; ++nt) b[nt] = *(const short8*)&Bs[(wc*4 + nt)*512 + lane*8];
        #pragma unroll
        for (int mt = 0; mt < 4; ++mt)
            #pragma unroll
            for (int nt = 0; nt < 4; ++nt)
                acc[mt][nt] = __builtin_amdgcn_mfma_f32_16x16x32_bf16(a[mt], b[nt], acc[mt][nt], 0, 0, 0);
    }

    #pragma unroll
    for (int mt = 0; mt < 4; ++mt) {
        const int rowb = row0 + wr*64 + mt*16 + quad*4;
        #pragma unroll
        for (int nt = 0; nt < 4; ++nt) {
            const int col = col0 + wc*64 + nt*16 + l15;
            floatx4 v = acc[mt][nt];
            const float g  = bnp[col] * INVC;
            const float be = bnp[Nc + col];
            #pragma unroll
            for (int r = 0; r < 4; ++r) {
                size_t off = (size_t)(rowb + r) * Nc + col;
                float v1 = v[r] * g + be;
                if (residF) v1 += residF[off];
                if (do_relu) v1 = fmaxf(v1, 0.f);
                if (outB) outB[off] = f2bf(v1);
                if (outF) outF[off] = v1;
            }
        }
    }
}

// standalone gemm (pqkv)
__global__ __launch_bounds__(256, 4) void gemm_bf16(
    const unsigned short* __restrict__ A, const unsigned short* __restrict__ Bt,
    const float* __restrict__ bnp, unsigned short* __restrict__ outB,
    int K, int Nc)
{
    __shared__ unsigned short As[8 * 512];
    __shared__ unsigned short Bs[8 * 512];
    gemm_body(A, Bt, bnp, nullptr, outB, nullptr, K, Nc, 0,
              blockIdx.y * 128, blockIdx.x * 128, As, Bs);
}

// ---------------------------------------------------------------------------
// L2: pix1 gemm (512 blocks) + mem_fused cast+mem1+mqkv (64 blocks)
// ---------------------------------------------------------------------------
__global__ __launch_bounds__(256) void k_pix1_memfused(
    const unsigned short* __restrict__ pixB, const unsigned short* __restrict__ Wt1,
    const float* __restrict__ bn_pix1, unsigned short* __restrict__ pixA,
    const float* __restrict__ memory_input,
    const unsigned short* __restrict__ Wt0, const float* __restrict__ bn1,
    const unsigned short* __restrict__ Wt2, const float* __restrict__ bnq,
    unsigned short* __restrict__ mqkv)
{
    __shared__ unsigned short As[8 * 512];
    __shared__ unsigned short Bs[8 * 512];
    const int bx = blockIdx.x;
    if (bx < 512) {
        gemm_body(pixB, Wt1, bn_pix1, nullptr, pixA, nullptr, 128, 256, 1,
                  (bx >> 1) * 128, (bx & 1) * 128, As, Bs);
        return;
    }
    // mem_fused
    unsigned short* A0 = As;       // 4*512
    unsigned short* A1 = Bs;       // 8*512
    const int t = threadIdx.x;
    const int lane = t & 63, w = t >> 6;
    const int l15 = lane & 15, quad = lane >> 4;
    const int g0 = (bx - 512) * 16;

    {   // cast 16x128 fp32 -> A-frag
        const int row = t >> 4;
        const int c0 = (t & 15) * 8;
        const float* src = memory_input + (size_t)(g0 + row) * 128 + c0;
        float4 v0 = *(const float4*)src;
        float4 v1 = *(const float4*)(src + 4);
        float vv[8] = {v0.x, v0.y, v0.z, v0.w, v1.x, v1.y, v1.z, v1.w};
        #pragma unroll
        for (int e = 0; e < 8; ++e)
            A0[fidx(row, c0 + e)] = f2bf(vv[e]);
    }
    __syncthreads();

    // mem1: M=16, N=256, K=128
    #pragma unroll
    for (int i = 0; i < 4; ++i) {
        const int n0 = (w*4 + i) * 16;
        floatx4 acc = {0.f,0.f,0.f,0.f};
        #pragma unroll
        for (int kc = 0; kc < 4; ++kc) {
            short8 a = *(const short8*)&A0[kc*512 + lane*8];
            short8 bfr = *(const short8*)&Wt0[(size_t)(n0 + l15)*128 + kc*32 + quad*8];
            acc = __builtin_amdgcn_mfma_f32_16x16x32_bf16(a, bfr, acc, 0, 0, 0);
        }
        const int col = n0 + l15;
        const float g = bn1[col] * INVC, be = bn1[256 + col];
        #pragma unroll
        for (int r = 0; r < 4; ++r) {
            const int row = quad*4 + r;
            float v = fmaxf(acc[r]*g + be, 0.f);
            A1[fidx(row, col)] = f2bf(v);
        }
    }
    __syncthreads();

    // mqkv: M=16, N=512, K=256
    #pragma unroll
    for (int i = 0; i < 8; ++i) {
        const int n0 = w*128 + i*16;
        floatx4 acc = {0.f,0.f,0.f,0.f};
        #pragma unroll
        for (int kc = 0; kc < 8; ++kc) {
            short8 a = *(const short8*)&A1[kc*512 + lane*8];
            short8 bfr = *(const short8*)&Wt2[(size_t)(n0 + l15)*256 + kc*32 + quad*8];
            acc = __builtin_amdgcn_mfma_f32_16x16x32_bf16(a, bfr, acc, 0, 0, 0);
        }
        const int col = n0 + l15;
        const float g = bnq[col] * INVC, be = bnq[512 + col];
        #pragma unroll
        for (int r = 0; r < 4; ++r) {
            const int row = quad*4 + r;
            mqkv[(size_t)(g0 + row)*512 + col] = f2bf(acc[r]*g + be);
        }
    }
}

// ---------------------------------------------------------------------------
// L4: unified attention. Every block: 64 queries x 128 keys, frag-ordered LDS.
//   bx < 4096:              pixel attn (sigmoid), write pret
//   bx >= 4096 (4224 blks): memory attn chunk (softmax partial), write parts
// LDS: Qs 4KB + Ks 8KB + VsT 8KB + Ps 16KB = 36KB -> 4 blocks/CU
// ---------------------------------------------------------------------------
__global__ __launch_bounds__(256, 4) void k_attn(
    const unsigned short* __restrict__ pqkv,
    const unsigned short* __restrict__ mqkv,
    const float* __restrict__ bn_psim, const float* __restrict__ bn_pret,
    unsigned short* __restrict__ pret,
    const float* __restrict__ bn_msim,
    float* __restrict__ part_acc, float* __restrict__ part_ml)
{
    __shared__ unsigned short Qs[4*512];     // 64 q x 32 k (upper 16 zero)
    __shared__ unsigned short Ks[8*512];     // 128 keys x 32 k (upper 16 zero)
    __shared__ unsigned short VsT[8*512];    // B-frag: 32 dv x 128 keys
    __shared__ unsigned short Ps[16*512];    // A-frag: 64 q x 128 keys
    const int t = threadIdx.x;
    const int lane = t & 63, w = t >> 6;
    const int l15 = lane & 15, quad = lane >> 4;
    floatx4 z4 = {0.f, 0.f, 0.f, 0.f};
    const uint4 zz = make_uint4(0u,0u,0u,0u);

    const int is_pix = (blockIdx.x < 4096);
    int b, h, qrow0;                  // query base (global row in its matrix)
    const unsigned short* kvbase;     // K/V source rows base (128 rows)
    if (is_pix) {
        const int bx = blockIdx.x;
        const int lt = bx & 63; h = (bx >> 6) & 7; b = bx >> 9;
        qrow0 = b*4096 + lt*64;
        kvbase = mqkv + ((size_t)(b*128) << 9);
    } else {
        const int bxm = blockIdx.x - 4096;
        const int c = bxm % NCHUNK;
        const int rest = bxm / NCHUNK;
        const int qh = rest & 1; h = (rest >> 1) & 7; b = rest >> 4;
        qrow0 = b*128 + qh*64;
        kvbase = (c < 32) ? (pqkv + ((size_t)(b*4096 + c*128) << 9))
                          : (mqkv + ((size_t)(b*128) << 9));
    }
    const unsigned short* qbase = is_pix ? pqkv : mqkv;

    // ---- loads ----
    {
        const int r = t >> 1, half = t & 1;      // r: 0..127
        if (t < 128) {   // Q: 64 rows
            const unsigned short* src = qbase + ((size_t)(qrow0 + r) << 9) + h*16 + half*8;
            *(uint4*)&Qs[(r>>4)*512 + ((r&15) + 16*half)*8] = *(const uint4*)src;
            *(uint4*)&Qs[(r>>4)*512 + ((r&15) + 16*(2+half))*8] = zz;
        }
        // K: 128 rows
        const unsigned short* ksrc = kvbase + ((size_t)r << 9) + 128 + h*16 + half*8;
        *(uint4*)&Ks[(r>>4)*512 + ((r&15) + 16*half)*8] = *(const uint4*)ksrc;
        *(uint4*)&Ks[(r>>4)*512 + ((r&15) + 16*(2+half))*8] = zz;
        // V: 128 rows x 32 dv -> B-frag VsT[nu=dv>>4][kc=r>>5]
        const unsigned short* vsrc = kvbase + ((size_t)r << 9) + 256 + h*32 + half*16;
        uint4 va = *(const uint4*)vsrc;
        uint4 vb = *(const uint4*)(vsrc + 8);
        unsigned short ev[16] = {
            (unsigned short)(va.x & 0xffffu), (unsigned short)(va.x >> 16),
            (unsigned short)(va.y & 0xffffu), (unsigned short)(va.y >> 16),
            (unsigned short)(va.z & 0xffffu), (unsigned short)(va.z >> 16),
            (unsigned short)(va.w & 0xffffu), (unsigned short)(va.w >> 16),
            (unsigned short)(vb.x & 0xffffu), (unsigned short)(vb.x >> 16),
            (unsigned short)(vb.y & 0xffffu), (unsigned short)(vb.y >> 16),
            (unsigned short)(vb.z & 0xffffu), (unsigned short)(vb.z >> 16),
            (unsigned short)(vb.w & 0xffffu), (unsigned short)(vb.w >> 16)};
        const int vbase_off = (half*4 + (r>>5))*512 + 16*((r>>3)&3)*8 + (r&7);
        #pragma unroll
        for (int e = 0; e < 16; ++e)
            VsT[vbase_off + e*8] = ev[e];
    }
    __syncthreads();

    // ---- S phase: wave w owns query rows [w*16, w*16+16) ----
    const float simg = (is_pix ? bn_psim[h] : bn_msim[h]) * INVC;
    const float simb =  is_pix ? bn_psim[8 + h] : bn_msim[8 + h];
    short8 aq = *(const short8*)&Qs[w*512 + lane*8];
    float mx4[4], ls4[4];

    if (is_pix) {
        #pragma unroll
        for (int nt = 0; nt < 8; ++nt) {
            short8 bk = *(const short8*)&Ks[nt*512 + lane*8];
            floatx4 s = __builtin_amdgcn_mfma_f32_16x16x32_bf16(aq, bk, z4, 0, 0, 0);
            const int pbase = (w*4 + (nt>>1))*512 + 16*((nt&1)*2 + (l15>>3))*8 + (l15&7);
            #pragma unroll
            for (int r = 0; r < 4; ++r) {
                float x = s[r] * simg + simb;
                float p = __builtin_amdgcn_rcpf(1.f + __expf(-x));
                Ps[pbase + (quad*4 + r)*8] = f2bf(p);
            }
        }
    } else {
        float sv[8][4];
        #pragma unroll
        for (int nt = 0; nt < 8; ++nt) {
            short8 bk = *(const short8*)&Ks[nt*512 + lane*8];
            floatx4 s = __builtin_amdgcn_mfma_f32_16x16x32_bf16(aq, bk, z4, 0, 0, 0);
            #pragma unroll
            for (int r = 0; r < 4; ++r) sv[nt][r] = s[r] * simg + simb;
        }
        #pragma unroll
        for (int r = 0; r < 4; ++r) {
            float mx = sv[0][r];
            #pragma unroll
            for (int nt = 1; nt < 8; ++nt) mx = fmaxf(mx, sv[nt][r]);
            mx = fmaxf(mx, __shfl_xor(mx, 1));
            mx = fmaxf(mx, __shfl_xor(mx, 2));
            mx = fmaxf(mx, __shfl_xor(mx, 4));
            mx = fmaxf(mx, __shfl_xor(mx, 8));
            float lsum = 0.f;
            #pragma unroll
            for (int nt = 0; nt < 8; ++nt) {
                float p = __expf(sv[nt][r] - mx);
                lsum += p;
                Ps[(w*4 + (nt>>1))*512 + ((quad*4+r) + 16*((nt&1)*2 + (l15>>3)))*8 + (l15&7)] = f2bf(p);
            }
            lsum += __shfl_xor(lsum, 1);
            lsum += __shfl_xor(lsum, 2);
            lsum += __shfl_xor(lsum, 4);
            lsum += __shfl_xor(lsum, 8);
            mx4[r] = mx; ls4[r] = lsum;
        }
    }

    // ---- PV: out tile 16q x 16dv x2, K=128 (same-wave LDS dep, no barrier) ----
    #pragma unroll
    for (int dvt = 0; dvt < 2; ++dvt) {
        floatx4 acc = {0.f,0.f,0.f,0.f};
        #pragma unroll
        for (int ks = 0; ks < 4; ++ks) {
            short8 ap = *(const short8*)&Ps[(w*4 + ks)*512 + lane*8];
            short8 bv = *(const short8*)&VsT[(dvt*4 + ks)*512 + lane*8];
            acc = __builtin_amdgcn_mfma_f32_16x16x32_bf16(ap, bv, acc, 0, 0, 0);
        }
        if (is_pix) {
            const int dv = dvt*16 + l15;
            const float g  = bn_pret[h*32 + dv] * INVC;
            const float be = bn_pret[256 + h*32 + dv];
            #pragma unroll
            for (int r = 0; r < 4; ++r) {
                const int row = qrow0 + w*16 + quad*4 + r;
                float v = fmaxf(acc[r] * g + be, 0.f);
                pret[((size_t)row << 8) + h*32 + dv] = f2bf(v);
            }
        } else {
            const int bxm = blockIdx.x - 4096;
            const int c = bxm % NCHUNK;
            const int rest = bxm / NCHUNK;
            const int qh = rest & 1;
            const int bh = b*8 + h;
            const int dv = dvt*16 + l15;
            #pragma unroll
            for (int r = 0; r < 4; ++r) {
                const int q = qh*64 + w*16 + quad*4 + r;
                part_acc[((size_t)(bh*NCHUNK + c)*128 + q)*32 + dv] = acc[r];
            }
        }
    }
    if (!is_pix && l15 == 0) {
        const int bxm = blockIdx.x - 4096;
        const int c = bxm % NCHUNK;
        const int rest = bxm / NCHUNK;
        const int qh = rest & 1;
        const int bh = b*8 + h;
        #pragma unroll
        for (int r = 0; r < 4; ++r) {
            const int q = qh*64 + w*16 + quad*4 + r;
            size_t o = ((size_t)(bh*NCHUNK + c)*128 + q) * 2;
            part_ml[o]     = mx4[r];
            part_ml[o + 1] = ls4[r];
        }
    }
}

// ---------------------------------------------------------------------------
// L5: pix3 gemm (256 blocks) + [flash-combine + mem3 -> moB] (64 blocks)
// ---------------------------------------------------------------------------
__global__ __launch_bounds__(256) void k_pix3_combmem3(
    const unsigned short* __restrict__ pretB, const unsigned short* __restrict__ Wt5,
    const float* __restrict__ bn_pix3, const float* __restrict__ pixel_input,
    float* __restrict__ out_pix,
    const float* __restrict__ part_acc, const float* __restrict__ part_ml,
    const float* __restrict__ bn_ret,
    const unsigned short* __restrict__ Wt4, const float* __restrict__ bn3,
    const float* __restrict__ memory_input,
    unsigned short* __restrict__ moB)
{
    __shared__ unsigned short As[8 * 512];
    __shared__ unsigned short Bs[8 * 512];
    const int bx = blockIdx.x;
    if (bx < 256) {
        gemm_body(pretB, Wt5, bn_pix3, pixel_input, nullptr, out_pix, 256, 128, 1,
                  bx * 128, 0, As, Bs);
        return;
    }
    unsigned short* mretA = As;    // 8*512
    const int t = threadIdx.x;
    const int lane = t & 63, w = t >> 6;
    const int l15 = lane & 15, quad = lane >> 4;
    const int g0 = (bx - 256) * 16;
    const int b = g0 >> 7;
    const int nbase = g0 & 127;

    {   // flash combine -> mretA (16 x 256)
        const int row = t >> 4;
        const int c0 = (t & 15) * 16;
        const int h = c0 >> 5;
        const int n = nbase + row;
        const int bh = b*8 + h;
        float m_g = -1e30f;
        for (int s = 0; s < NCHUNK; ++s)
            m_g = fmaxf(m_g, part_ml[((size_t)(bh*NCHUNK + s)*128 + n)*2]);
        float l_g = 0.f;
        float og[16];
        #pragma unroll
        for (int e = 0; e < 16; ++e) og[e] = 0.f;
        for (int s = 0; s < NCHUNK; ++s) {
            size_t o = ((size_t)(bh*NCHUNK + s)*128 + n)*2;
            float wgt = __expf(part_ml[o] - m_g);
            l_g += part_ml[o+1] * wgt;
            const float* pa = part_acc + ((size_t)(bh*NCHUNK + s)*128 + n)*32 + (c0 & 31);
            #pragma unroll
            for (int e = 0; e < 16; e += 4) {
                float4 v = *(const float4*)(pa + e);
                og[e]   += v.x*wgt; og[e+1] += v.y*wgt;
                og[e+2] += v.z*wgt; og[e+3] += v.w*wgt;
            }
        }
        float invl = __builtin_amdgcn_rcpf(l_g);
        #pragma unroll
        for (int e = 0; e < 16; ++e) {
            int col = c0 + e;
            int dv = col & 31;
            float v = og[e]*invl*(bn_ret[h*32+dv]*INVC) + bn_ret[256 + h*32 + dv];
            mretA[fidx(row, col)] = f2bf(fmaxf(v, 0.f));
        }
    }
    __syncthreads();

    // mem3: M=16,N=128,K=256 -> moB (bf16, relu(resid))
    #pragma unroll
    for (int i = 0; i < 2; ++i) {
        const int n0 = (w*2 + i) * 16;
        floatx4 acc = {0.f,0.f,0.f,0.f};
        #pragma unroll
        for (int kc = 0; kc < 8; ++kc) {
            short8 a = *(const short8*)&mretA[kc*512 + lane*8];
            short8 bfr = *(const short8*)&Wt4[(size_t)(n0 + l15)*256 + kc*32 + quad*8];
            acc = __builtin_amdgcn_mfma_f32_16x16x32_bf16(a, bfr, acc, 0, 0, 0);
        }
        const int col = n0 + l15;
        const float g = bn3[col]*INVC, be = bn3[128 + col];
        #pragma unroll
        for (int r = 0; r < 4; ++r) {
            const int row = quad*4 + r;
            float v = acc[r]*g + be + memory_input[(size_t)(g0 + row)*128 + col];
            moB[(size_t)(g0 + row)*128 + col] = f2bf(fmaxf(v, 0.f));
        }
    }
}

// ---------------------------------------------------------------------------
// L6: ffn1+ffn2, 64 blocks x 1024 threads (16 waves)
// ---------------------------------------------------------------------------
__global__ __launch_bounds__(1024) void k_ffn(
    const unsigned short* __restrict__ moB,
    const unsigned short* __restrict__ Wt6, const float* __restrict__ bnf1,
    const unsigned short* __restrict__ Wt7, const float* __restrict__ bnf2,
    float* __restrict__ out_mem)
{
    __shared__ unsigned short moA[4*512];
    __shared__ unsigned short fA[64*512];
    __shared__ floatx4 red[2][8][64];
    const int t = threadIdx.x;
    const int lane = t & 63, w = t >> 6;      // 16 waves
    const int l15 = lane & 15, quad = lane >> 4;
    const int g0 = blockIdx.x * 16;

    if (t < 256) {  // load moB 16x128 -> A-frag
        const int row = t >> 4;
        const int c0 = (t & 15) * 8;
        uint4 v = *(const uint4*)(moB + (size_t)(g0 + row)*128 + c0);
        unsigned short e0 = (unsigned short)(v.x & 0xffffu), e1 = (unsigned short)(v.x >> 16);
        unsigned short e2 = (unsigned short)(v.y & 0xffffu), e3 = (unsigned short)(v.y >> 16);
        unsigned short e4 = (unsigned short)(v.z & 0xffffu), e5 = (unsigned short)(v.z >> 16);
        unsigned short e6 = (unsigned short)(v.w & 0xffffu), e7 = (unsigned short)(v.w >> 16);
        moA[fidx(row, c0+0)] = e0; moA[fidx(row, c0+1)] = e1;
        moA[fidx(row, c0+2)] = e2; moA[fidx(row, c0+3)] = e3;
        moA[fidx(row, c0+4)] = e4; moA[fidx(row, c0+5)] = e5;
        moA[fidx(row, c0+6)] = e6; moA[fidx(row, c0+7)] = e7;
    }
    __syncthreads();

    // ffn1: M=16, N=2048, K=128; wave w covers n in [w*128, (w+1)*128)
    #pragma unroll
    for (int i = 0; i < 8; ++i) {
        const int n0 = (w*8 + i) * 16;
        floatx4 acc = {0.f,0.f,0.f,0.f};
        #pragma unroll
        for (int kc = 0; kc < 4; ++kc) {
            short8 a = *(const short8*)&moA[kc*512 + lane*8];
            short8 bfr = *(const short8*)&Wt6[(size_t)(n0 + l15)*128 + kc*32 + quad*8];
            acc = __builtin_amdgcn_mfma_f32_16x16x32_bf16(a, bfr, acc, 0, 0, 0);
        }
        const int col = n0 + l15;
        const float g = bnf1[col]*INVC, be = bnf1[2048 + col];
        #pragma unroll
        for (int r = 0; r < 4; ++r)
            fA[fidx(quad*4 + r, col)] = f2bf(fmaxf(acc[r]*g + be, 0.f));
    }
    __syncthreads();

    // ffn2: M=16, N=128, K=2048; wave w: ntile = w&7, k-half = w>>3
    {
        const int ntile = w & 7, khalf = w >> 3;
        const int n0 = ntile * 16;
        floatx4 acc = {0.f,0.f,0.f,0.f};
        #pragma unroll 8
        for (int kc = 0; kc < 32; ++kc) {
            const int kcu = khalf*32 + kc;
            short8 a = *(const short8*)&fA[kcu*512 + lane*8];
            short8 bfr = *(const short8*)&Wt7[(size_t)(n0 + l15)*2048 + kcu*32 + quad*8];
            acc = __builtin_amdgcn_mfma_f32_16x16x32_bf16(a, bfr, acc, 0, 0, 0);
        }
        red[khalf][ntile][lane] = acc;
    }
    __syncthreads();
    if (w < 8) {
        const int n0 = w * 16;
        floatx4 s0 = red[0][w][lane];
        floatx4 s1 = red[1][w][lane];
        const int col = n0 + l15;
        const float g = bnf2[col]*INVC, be = bnf2[128 + col];
        #pragma unroll
        for (int r = 0; r < 4; ++r) {
            const int row = quad*4 + r;
            float resid = bf2f(moA[fidx(row, col)]);
            float v = fmaxf((s0[r] + s1[r])*g + be + resid, 0.f);
            out_mem[(size_t)(g0 + row)*128 + col] = v;
        }
    }
}

// ---------------------------------------------------------------------------
extern "C" void kernel_launch(void* const* d_in, const int* in_sizes, int n_in,
                              void* d_out, int out_size, void* d_ws, size_t ws_size,
                              hipStream_t stream) {
    const float* pixel_input  = (const float*)d_in[0];
    const float* memory_input = (const float*)d_in[1];
    const float* W_mem1    = (const float*)d_in[2];
    const float* bn_mem1   = (const float*)d_in[3];
    const float* W_pix1    = (const float*)d_in[4];
    const float* bn_pix1   = (const float*)d_in[5];
    const float* W_mem_qkv = (const float*)d_in[6];
    const float* bn_mem_qkv= (const float*)d_in[7];
    const float* W_pix_qkv = (const float*)d_in[8];
    const float* bn_pix_qkv= (const float*)d_in[9];
    const float* bn_mem_sim= (const float*)d_in[10];
    const float* bn_mem_ret= (const float*)d_in[11];
    const float* bn_pix_sim= (const float*)d_in[12];
    const float* bn_pix_ret= (const float*)d_in[13];
    const float* W_mem3    = (const float*)d_in[14];
    const float* bn_mem3   = (const float*)d_in[15];
    const float* W_pix3    = (const float*)d_in[16];
    const float* bn_pix3   = (const float*)d_in[17];
    const float* W_ffn1    = (const float*)d_in[18];
    const float* bn_ffn1   = (const float*)d_in[19];
    const float* W_ffn2    = (const float*)d_in[20];
    const float* bn_ffn2   = (const float*)d_in[21];

    char* ws = (char*)d_ws;
    size_t off = 0;
    auto alloc = [&](size_t bytes) -> void* {
        void* p = ws + off; off += (bytes + 255) & ~(size_t)255; return p;
    };
    unsigned short* pixB  = (unsigned short*)alloc((size_t)32768*128*2);
    unsigned short* Wt0   = (unsigned short*)alloc((size_t)256*128*2);
    unsigned short* Wt1   = (unsigned short*)alloc((size_t)256*128*2);
    unsigned short* Wt2   = (unsigned short*)alloc((size_t)512*256*2);
    unsigned short* Wt3   = (unsigned short*)alloc((size_t)512*256*2);
    unsigned short* Wt4   = (unsigned short*)alloc((size_t)128*256*2);
    unsigned short* Wt5   = (unsigned short*)alloc((size_t)128*256*2);
    unsigned short* Wt6   = (unsigned short*)alloc((size_t)2048*128*2);
    unsigned short* Wt7   = (unsigned short*)alloc((size_t)128*2048*2);
    unsigned short* mqkvB = (unsigned short*)alloc((size_t)1024*512*2);
    unsigned short* pixA  = (unsigned short*)alloc((size_t)32768*256*2);
    unsigned short* pqkvB = (unsigned short*)alloc((size_t)32768*512*2);
    float* part_acc = (float*)alloc((size_t)64*NCHUNK*128*32*4);
    float* part_ml  = (float*)alloc((size_t)64*NCHUNK*128*2*4);
    unsigned short* pretB = (unsigned short*)alloc((size_t)32768*256*2);
    unsigned short* moB   = (unsigned short*)alloc((size_t)1024*128*2);

    float* out_pix = (float*)d_out;
    float* out_mem = (float*)d_out + (size_t)8*4096*128;

    PrepPtrs P;
    P.src_pix = pixel_input;
    P.dst_pix = pixB;
    P.W[0]=W_mem1; P.W[1]=W_pix1; P.W[2]=W_mem_qkv; P.W[3]=W_pix_qkv;
    P.W[4]=W_mem3; P.W[5]=W_pix3; P.W[6]=W_ffn1;    P.W[7]=W_ffn2;
    P.Wt[0]=Wt0; P.Wt[1]=Wt1; P.Wt[2]=Wt2; P.Wt[3]=Wt3;
    P.Wt[4]=Wt4; P.Wt[5]=Wt5; P.Wt[6]=Wt6; P.Wt[7]=Wt7;

    dim3 blk(256);
    // L1: casts + weight transposes
    prep_kernel<<<4992, blk, 0, stream>>>(P);
    // L2: pix1 gemm + mem front (cast+mem1+mqkv)
    k_pix1_memfused<<<576, blk, 0, stream>>>(pixB, Wt1, bn_pix1, pixA,
        memory_input, Wt0, bn_mem1, Wt2, bn_mem_qkv, mqkvB);
    // L3: pqkv gemm [32768 x 512, K=256]
    gemm_bf16<<<dim3(4,256,1), blk, 0, stream>>>(pixA, Wt3, bn_pix_qkv, pqkvB, 256, 512);
    // L4: unified attention (pix sigmoid 4096 blocks + mem chunks 4224 blocks)
    k_attn<<<4096 + 128*NCHUNK, blk, 0, stream>>>(pqkvB, mqkvB,
        bn_pix_sim, bn_pix_ret, pretB, bn_mem_sim, part_acc, part_ml);
    // L5: pix3 gemm (+resid,relu -> out_pix) + combine+mem3 -> moB
    k_pix3_combmem3<<<320, blk, 0, stream>>>(pretB, Wt5, bn_pix3, pixel_input, out_pix,
        part_acc, part_ml, bn_mem_ret, Wt4, bn_mem3, memory_input, moB);
    // L6: ffn1+ffn2 -> out_mem
    k_ffn<<<64, dim3(1024), 0, stream>>>(moB, Wt6, bn_ffn1, Wt7, bn_ffn2, out_mem);
}

// Round 7
// 238.053 us; speedup vs baseline: 1.1104x; 1.1104x over previous
//
#include <hip/hip_runtime.h>

typedef __attribute__((ext_vector_type(8))) short short8;
typedef __attribute__((ext_vector_type(4))) float floatx4;

#define INVC 0.9995003746877732f
#define NCHUNK 33

__device__ __forceinline__ unsigned short f2bf(float f) {
    union { float f; unsigned int u; } c; c.f = f;
    unsigned int r = c.u + 0x7fffu + ((c.u >> 16) & 1u);
    return (unsigned short)(r >> 16);
}
__device__ __forceinline__ unsigned int f2bf2(float a, float b) {
    return (unsigned int)f2bf(a) | ((unsigned int)f2bf(b) << 16);
}
__device__ __forceinline__ float bf2f(unsigned short u) {
    union { unsigned int u; float f; } c; c.u = ((unsigned int)u) << 16;
    return c.f;
}
__device__ __forceinline__ void gld_lds16(const unsigned short* g, unsigned short* l) {
    __builtin_amdgcn_global_load_lds(
        (const __attribute__((address_space(1))) unsigned int*)g,
        (__attribute__((address_space(3))) unsigned int*)l, 16, 0, 0);
}
// A/B-frag index: element (idx in 16-wide unit, k) -> offset; unit stride 512
__device__ __forceinline__ int fidx(int row, int k) {
    return (k >> 5) * 512 + (row + 16 * ((k >> 3) & 3)) * 8 + (k & 7);
}

// ---------------------------------------------------------------------------
// Prep: fp32->bf16 cast of pixel input + transpose-cast of 8 weight matrices
// ---------------------------------------------------------------------------
struct PrepPtrs {
    const float* src_pix;
    unsigned short* dst_pix;
    const float* W[8]; unsigned short* Wt[8];
};

__global__ __launch_bounds__(256) void prep_kernel(PrepPtrs P) {
    __shared__ float T[32][33];
    const int bid = blockIdx.x, t = threadIdx.x;
    if (bid < 4096) {
        int i = bid * 1024 + t * 4;
        float4 v = *(const float4*)(P.src_pix + i);
        unsigned long long pk = (unsigned long long)f2bf(v.x)
            | ((unsigned long long)f2bf(v.y) << 16)
            | ((unsigned long long)f2bf(v.z) << 32)
            | ((unsigned long long)f2bf(v.w) << 48);
        *(unsigned long long*)(P.dst_pix + i) = pk;
        return;
    }
    int rel = bid - 4096;
    const int KD[8]  = {128,128,256,256,256,256,128,2048};
    const int ND[8]  = {256,256,512,512,128,128,2048,128};
    const int CNT[8] = {32,32,128,128,32,32,256,256};
    int wi = 0;
    #pragma unroll
    for (int k = 0; k < 8; ++k) { if (rel >= CNT[k] && wi == k) { rel -= CNT[k]; wi = k + 1; } }
    const int K = KD[wi], N = ND[wi];
    const int ntn = N >> 5;
    const int tn = rel % ntn, tk = rel / ntn;
    const int n0 = tn * 32, k0 = tk * 32;
    const float* W = P.W[wi];
    unsigned short* Wt = P.Wt[wi];
    const int tx = t & 31, ty = t >> 5;
    #pragma unroll
    for (int i = 0; i < 4; ++i)
        T[ty + 8*i][tx] = W[(size_t)(k0 + ty + 8*i) * N + n0 + tx];
    __syncthreads();
    #pragma unroll
    for (int i = 0; i < 4; ++i)
        Wt[(size_t)(n0 + ty + 8*i) * K + k0 + tx] = f2bf(T[tx][ty + 8*i]);
}

// ---------------------------------------------------------------------------
// gemm device body (used by pix3): 128x128 tile, BK=32, frag-ordered LDS
// ---------------------------------------------------------------------------
__device__ __forceinline__ void gemm_body(
    const unsigned short* __restrict__ A,
    const unsigned short* __restrict__ Bt,
    const float* __restrict__ bnp,
    const float* __restrict__ residF,
    float* __restrict__ outF,
    int K, int Nc, int row0, int col0,
    unsigned short* As, unsigned short* Bs)
{
    const int t = threadIdx.x;
    const int lane = t & 63, w = t >> 6;
    const int l15 = lane & 15, quad = lane >> 4;
    const int wr = w >> 1, wc = w & 1;

    floatx4 acc[4][4];
    #pragma unroll
    for (int i = 0; i < 4; ++i)
        #pragma unroll
        for (int j = 0; j < 4; ++j) acc[i][j] = (floatx4){0.f, 0.f, 0.f, 0.f};

    const unsigned short* gA0 = A  + (size_t)(row0 + w*16     + l15) * K + quad*8;
    const unsigned short* gA1 = A  + (size_t)(row0 + (w+4)*16 + l15) * K + quad*8;
    const unsigned short* gB0 = Bt + (size_t)(col0 + w*16     + l15) * K + quad*8;
    const unsigned short* gB1 = Bt + (size_t)(col0 + (w+4)*16 + l15) * K + quad*8;
    unsigned short* lA0 = &As[w * 512];
    unsigned short* lA1 = &As[(w + 4) * 512];
    unsigned short* lB0 = &Bs[w * 512];
    unsigned short* lB1 = &Bs[(w + 4) * 512];

    for (int k0 = 0; k0 < K; k0 += 32) {
        __syncthreads();
        gld_lds16(gA0 + k0, lA0);
        gld_lds16(gA1 + k0, lA1);
        gld_lds16(gB0 + k0, lB0);
        gld_lds16(gB1 + k0, lB1);
        __syncthreads();
        short8 a[4], b[4];
        #pragma unroll
        for (int mt = 0; mt < 4; ++mt) a[mt] = *(const short8*)&As[(wr*4 + mt)*512 + lane*8];
        #pragma unroll
        for (int nt = 0; nt < 4; ++nt) b[nt] = *(const short8*)&Bs[(wc*4 + nt)*512 + lane*8];
        #pragma unroll
        for (int mt = 0; mt < 4; ++mt)
            #pragma unroll
            for (int nt = 0; nt < 4; ++nt)
                acc[mt][nt] = __builtin_amdgcn_mfma_f32_16x16x32_bf16(a[mt], b[nt], acc[mt][nt], 0, 0, 0);
    }

    #pragma unroll
    for (int mt = 0; mt < 4; ++mt) {
        const int rowb = row0 + wr*64 + mt*16 + quad*4;
        #pragma unroll
        for (int nt = 0; nt < 4; ++nt) {
            const int col = col0 + wc*64 + nt*16 + l15;
            floatx4 v = acc[mt][nt];
            const float g  = bnp[col] * INVC;
            const float be = bnp[Nc + col];
            #pragma unroll
            for (int r = 0; r < 4; ++r) {
                size_t off = (size_t)(rowb + r) * Nc + col;
                float v1 = v[r] * g + be + residF[off];
                outF[off] = fmaxf(v1, 0.f);
            }
        }
    }
}

// ---------------------------------------------------------------------------
// L2: k_qkv — fused pix1+pqkv (256 blocks x 128 rows) + mem front (64 blocks)
// Phase A computes pix^T (A=Wt1, B=pixB rows) so C packs into a B-frag via
// ds_write_b64 (no scatter). Phase B: pqkv^T (A=Wt2 from L2, B=pix from LDS).
// ---------------------------------------------------------------------------
__global__ __launch_bounds__(256) void k_qkv(
    const unsigned short* __restrict__ pixB,
    const unsigned short* __restrict__ Wt1, const float* __restrict__ bn1,
    const unsigned short* __restrict__ Wt2, const float* __restrict__ bnq,
    unsigned short* __restrict__ pqkvB,
    const float* __restrict__ memory_input,
    const unsigned short* __restrict__ Wm0, const float* __restrict__ bnm1,
    const unsigned short* __restrict__ Wm2, const float* __restrict__ bnmq,
    unsigned short* __restrict__ mqkv)
{
    __shared__ unsigned short A2[64*512];   // 64 KB: pix[128 rows][256 k] B-frag (lane=row)
    const int t = threadIdx.x;
    const int lane = t & 63, w = t >> 6;
    const int l15 = lane & 15, quad = lane >> 4;

    if (blockIdx.x < 256) {
        const int row0 = blockIdx.x * 128;
        // ---- phase A: pix1^T: wave w owns k2 cols [w*64, w*64+64) ----
        short8 afr[4][4];
        float ga[4][4], ba[4][4];
        #pragma unroll
        for (int i = 0; i < 4; ++i) {
            #pragma unroll
            for (int kc = 0; kc < 4; ++kc)
                afr[i][kc] = *(const short8*)&Wt1[(size_t)(w*64 + i*16 + l15)*128 + kc*32 + quad*8];
            #pragma unroll
            for (int r = 0; r < 4; ++r) {
                const int col = w*64 + i*16 + quad*4 + r;
                ga[i][r] = bn1[col] * INVC;
                ba[i][r] = bn1[256 + col];
            }
        }
        #pragma unroll
        for (int ru = 0; ru < 8; ++ru) {
            short8 bfr[4];
            #pragma unroll
            for (int kc = 0; kc < 4; ++kc)
                bfr[kc] = *(const short8*)&pixB[(size_t)(row0 + ru*16 + l15)*128 + kc*32 + quad*8];
            #pragma unroll
            for (int i = 0; i < 4; ++i) {
                floatx4 acc = {0.f,0.f,0.f,0.f};
                #pragma unroll
                for (int kc = 0; kc < 4; ++kc)
                    acc = __builtin_amdgcn_mfma_f32_16x16x32_bf16(afr[i][kc], bfr[kc], acc, 0, 0, 0);
                float v[4];
                #pragma unroll
                for (int r = 0; r < 4; ++r)
                    v[r] = fmaxf(acc[r]*ga[i][r] + ba[i][r], 0.f);
                // k2 = w*64 + i*16 + quad*4 (+r); pack -> b64 into A2 B-frag
                const int unit = ru*8 + w*2 + (i >> 1);
                const int koff = (i & 1)*2 + (quad >> 1);
                const int off  = unit*512 + (l15 + 16*koff)*8 + (quad & 1)*4;
                uint2 pk; pk.x = f2bf2(v[0], v[1]); pk.y = f2bf2(v[2], v[3]);
                *(uint2*)&A2[off] = pk;
            }
        }
        __syncthreads();

        // ---- phase B: pqkv^T: wave w owns oc [w*128, w*128+128) ----
        #pragma unroll
        for (int op = 0; op < 4; ++op) {     // oct pairs
            short8 a0[8], a1[8];
            float g2[2][4], b2[2][4];
            #pragma unroll
            for (int kc = 0; kc < 8; ++kc) {
                a0[kc] = *(const short8*)&Wt2[(size_t)(w*128 + (op*2+0)*16 + l15)*256 + kc*32 + quad*8];
                a1[kc] = *(const short8*)&Wt2[(size_t)(w*128 + (op*2+1)*16 + l15)*256 + kc*32 + quad*8];
            }
            #pragma unroll
            for (int e = 0; e < 2; ++e)
                #pragma unroll
                for (int r = 0; r < 4; ++r) {
                    const int col = w*128 + (op*2+e)*16 + quad*4 + r;
                    g2[e][r] = bnq[col] * INVC;
                    b2[e][r] = bnq[512 + col];
                }
            #pragma unroll
            for (int ru = 0; ru < 8; ++ru) {
                short8 b[8];
                #pragma unroll
                for (int kc = 0; kc < 8; ++kc)
                    b[kc] = *(const short8*)&A2[(ru*8 + kc)*512 + lane*8];
                floatx4 acc0 = {0.f,0.f,0.f,0.f}, acc1 = {0.f,0.f,0.f,0.f};
                #pragma unroll
                for (int kc = 0; kc < 8; ++kc) {
                    acc0 = __builtin_amdgcn_mfma_f32_16x16x32_bf16(a0[kc], b[kc], acc0, 0, 0, 0);
                    acc1 = __builtin_amdgcn_mfma_f32_16x16x32_bf16(a1[kc], b[kc], acc1, 0, 0, 0);
                }
                const int row = row0 + ru*16 + l15;
                unsigned long long pk0 =
                    (unsigned long long)f2bf2(acc0[0]*g2[0][0]+b2[0][0], acc0[1]*g2[0][1]+b2[0][1])
                  | ((unsigned long long)f2bf2(acc0[2]*g2[0][2]+b2[0][2], acc0[3]*g2[0][3]+b2[0][3]) << 32);
                unsigned long long pk1 =
                    (unsigned long long)f2bf2(acc1[0]*g2[1][0]+b2[1][0], acc1[1]*g2[1][1]+b2[1][1])
                  | ((unsigned long long)f2bf2(acc1[2]*g2[1][2]+b2[1][2], acc1[3]*g2[1][3]+b2[1][3]) << 32);
                *(unsigned long long*)&pqkvB[(size_t)row*512 + w*128 + (op*2+0)*16 + quad*4] = pk0;
                *(unsigned long long*)&pqkvB[(size_t)row*512 + w*128 + (op*2+1)*16 + quad*4] = pk1;
            }
        }
        return;
    }

    // ---- mem front: cast + mem1 + mqkv (64 blocks x 16 rows) ----
    unsigned short* A0 = &A2[0];        // 4*512
    unsigned short* A1 = &A2[4*512];    // 8*512
    const int g0 = (blockIdx.x - 256) * 16;
    {
        const int row = t >> 4;
        const int c0 = (t & 15) * 8;
        const float* src = memory_input + (size_t)(g0 + row) * 128 + c0;
        float4 v0 = *(const float4*)src;
        float4 v1 = *(const float4*)(src + 4);
        float vv[8] = {v0.x, v0.y, v0.z, v0.w, v1.x, v1.y, v1.z, v1.w};
        #pragma unroll
        for (int e = 0; e < 8; ++e)
            A0[fidx(row, c0 + e)] = f2bf(vv[e]);
    }
    __syncthreads();
    #pragma unroll
    for (int i = 0; i < 4; ++i) {
        const int n0 = (w*4 + i) * 16;
        floatx4 acc = {0.f,0.f,0.f,0.f};
        #pragma unroll
        for (int kc = 0; kc < 4; ++kc) {
            short8 a = *(const short8*)&A0[kc*512 + lane*8];
            short8 bfr = *(const short8*)&Wm0[(size_t)(n0 + l15)*128 + kc*32 + quad*8];
            acc = __builtin_amdgcn_mfma_f32_16x16x32_bf16(a, bfr, acc, 0, 0, 0);
        }
        const int col = n0 + l15;
        const float g = bnm1[col] * INVC, be = bnm1[256 + col];
        #pragma unroll
        for (int r = 0; r < 4; ++r)
            A1[fidx(quad*4 + r, col)] = f2bf(fmaxf(acc[r]*g + be, 0.f));
    }
    __syncthreads();
    #pragma unroll
    for (int i = 0; i < 8; ++i) {
        const int n0 = w*128 + i*16;
        floatx4 acc = {0.f,0.f,0.f,0.f};
        #pragma unroll
        for (int kc = 0; kc < 8; ++kc) {
            short8 a = *(const short8*)&A1[kc*512 + lane*8];
            short8 bfr = *(const short8*)&Wm2[(size_t)(n0 + l15)*256 + kc*32 + quad*8];
            acc = __builtin_amdgcn_mfma_f32_16x16x32_bf16(a, bfr, acc, 0, 0, 0);
        }
        const int col = n0 + l15;
        const float g = bnmq[col] * INVC, be = bnmq[512 + col];
        #pragma unroll
        for (int r = 0; r < 4; ++r)
            mqkv[(size_t)(g0 + quad*4 + r)*512 + col] = f2bf(acc[r]*g + be);
    }
}

// ---------------------------------------------------------------------------
// L4: unified attention, S^T formulation (no scalar LDS scatter).
//   S^T = K Q^T  (A=K, B=Q) -> C: row=key, col=query -> b64 pack into P^T B-frag
//   out^T = V^T P^T (A=VsT, B=P^T) -> C: row=dv, col=query -> packed stores
// ---------------------------------------------------------------------------
__global__ __launch_bounds__(256, 4) void k_attn(
    const unsigned short* __restrict__ pqkv,
    const unsigned short* __restrict__ mqkv,
    const float* __restrict__ bn_psim, const float* __restrict__ bn_pret,
    unsigned short* __restrict__ pret,
    const float* __restrict__ bn_msim,
    float* __restrict__ part_acc, float* __restrict__ part_ml)
{
    __shared__ unsigned short Qs[4*512];     // 64 q x 32 k (upper 16 zero)  B-frag
    __shared__ unsigned short Ks[8*512];     // 128 keys x 32 k (upper 16 zero) A-frag
    __shared__ unsigned short VsT[8*512];    // A-frag: 32 dv x 128 keys
    __shared__ unsigned short Ps[16*512];    // per-wave B-frag: P^T 16 q x 128 keys
    const int t = threadIdx.x;
    const int lane = t & 63, w = t >> 6;
    const int l15 = lane & 15, quad = lane >> 4;
    floatx4 z4 = {0.f, 0.f, 0.f, 0.f};
    const uint4 zz = make_uint4(0u,0u,0u,0u);

    const int is_pix = (blockIdx.x < 4096);
    int b, h, qrow0, c = 0, qh = 0;
    const unsigned short* kvbase;
    if (is_pix) {
        const int bx = blockIdx.x;
        const int lt = bx & 63; h = (bx >> 6) & 7; b = bx >> 9;
        qrow0 = b*4096 + lt*64;
        kvbase = mqkv + ((size_t)(b*128) << 9);
    } else {
        const int bxm = blockIdx.x - 4096;
        c = bxm % NCHUNK;
        const int rest = bxm / NCHUNK;
        qh = rest & 1; h = (rest >> 1) & 7; b = rest >> 4;
        qrow0 = b*128 + qh*64;
        kvbase = (c < 32) ? (pqkv + ((size_t)(b*4096 + c*128) << 9))
                          : (mqkv + ((size_t)(b*128) << 9));
    }
    const unsigned short* qbase = is_pix ? pqkv : mqkv;

    // ---- loads (layouts unchanged from R6) ----
    {
        const int r = t >> 1, half = t & 1;
        if (t < 128) {
            const unsigned short* src = qbase + ((size_t)(qrow0 + r) << 9) + h*16 + half*8;
            *(uint4*)&Qs[(r>>4)*512 + ((r&15) + 16*half)*8] = *(const uint4*)src;
            *(uint4*)&Qs[(r>>4)*512 + ((r&15) + 16*(2+half))*8] = zz;
        }
        const unsigned short* ksrc = kvbase + ((size_t)r << 9) + 128 + h*16 + half*8;
        *(uint4*)&Ks[(r>>4)*512 + ((r&15) + 16*half)*8] = *(const uint4*)ksrc;
        *(uint4*)&Ks[(r>>4)*512 + ((r&15) + 16*(2+half))*8] = zz;
        const unsigned short* vsrc = kvbase + ((size_t)r << 9) + 256 + h*32 + half*16;
        uint4 va = *(const uint4*)vsrc;
        uint4 vb = *(const uint4*)(vsrc + 8);
        unsigned short ev[16] = {
            (unsigned short)(va.x & 0xffffu), (unsigned short)(va.x >> 16),
            (unsigned short)(va.y & 0xffffu), (unsigned short)(va.y >> 16),
            (unsigned short)(va.z & 0xffffu), (unsigned short)(va.z >> 16),
            (unsigned short)(va.w & 0xffffu), (unsigned short)(va.w >> 16),
            (unsigned short)(vb.x & 0xffffu), (unsigned short)(vb.x >> 16),
            (unsigned short)(vb.y & 0xffffu), (unsigned short)(vb.y >> 16),
            (unsigned short)(vb.z & 0xffffu), (unsigned short)(vb.z >> 16),
            (unsigned short)(vb.w & 0xffffu), (unsigned short)(vb.w >> 16)};
        const int vbase_off = (half*4 + (r>>5))*512 + 16*((r>>3)&3)*8 + (r&7);
        #pragma unroll
        for (int e = 0; e < 16; ++e)
            VsT[vbase_off + e*8] = ev[e];
    }
    __syncthreads();

    // ---- S^T phase: wave w owns queries [w*16, w*16+16); lane l15 = query ----
    const float simg = (is_pix ? bn_psim[h] : bn_msim[h]) * INVC;
    const float simb =  is_pix ? bn_psim[8 + h] : bn_msim[8 + h];
    short8 bq = *(const short8*)&Qs[w*512 + lane*8];
    float mstat, lstat;

    if (is_pix) {
        #pragma unroll
        for (int nt = 0; nt < 8; ++nt) {
            short8 ak = *(const short8*)&Ks[nt*512 + lane*8];
            floatx4 s = __builtin_amdgcn_mfma_f32_16x16x32_bf16(ak, bq, z4, 0, 0, 0);
            float p[4];
            #pragma unroll
            for (int r = 0; r < 4; ++r) {
                float x = s[r] * simg + simb;
                p[r] = __builtin_amdgcn_rcpf(1.f + __expf(-x));
            }
            const int off = (w*4 + (nt>>1))*512
                          + (l15 + 16*((nt&1)*2 + (quad>>1)))*8 + (quad&1)*4;
            uint2 pk; pk.x = f2bf2(p[0], p[1]); pk.y = f2bf2(p[2], p[3]);
            *(uint2*)&Ps[off] = pk;
        }
    } else {
        floatx4 sv[8];
        float mx = -1e30f;
        #pragma unroll
        for (int nt = 0; nt < 8; ++nt) {
            short8 ak = *(const short8*)&Ks[nt*512 + lane*8];
            floatx4 s = __builtin_amdgcn_mfma_f32_16x16x32_bf16(ak, bq, z4, 0, 0, 0);
            #pragma unroll
            for (int r = 0; r < 4; ++r) {
                sv[nt][r] = s[r] * simg + simb;
                mx = fmaxf(mx, sv[nt][r]);
            }
        }
        mx = fmaxf(mx, __shfl_xor(mx, 16));
        mx = fmaxf(mx, __shfl_xor(mx, 32));
        float lsum = 0.f;
        #pragma unroll
        for (int nt = 0; nt < 8; ++nt) {
            float p[4];
            #pragma unroll
            for (int r = 0; r < 4; ++r) {
                p[r] = __expf(sv[nt][r] - mx);
                lsum += p[r];
            }
            const int off = (w*4 + (nt>>1))*512
                          + (l15 + 16*((nt&1)*2 + (quad>>1)))*8 + (quad&1)*4;
            uint2 pk; pk.x = f2bf2(p[0], p[1]); pk.y = f2bf2(p[2], p[3]);
            *(uint2*)&Ps[off] = pk;
        }
        lsum += __shfl_xor(lsum, 16);
        lsum += __shfl_xor(lsum, 32);
        mstat = mx; lstat = lsum;
    }

    // ---- PV: out^T = V^T P^T (same-wave LDS dep, no barrier) ----
    #pragma unroll
    for (int dvt = 0; dvt < 2; ++dvt) {
        floatx4 acc = {0.f,0.f,0.f,0.f};
        #pragma unroll
        for (int ks = 0; ks < 4; ++ks) {
            short8 av = *(const short8*)&VsT[(dvt*4 + ks)*512 + lane*8];
            short8 bp = *(const short8*)&Ps[(w*4 + ks)*512 + lane*8];
            acc = __builtin_amdgcn_mfma_f32_16x16x32_bf16(av, bp, acc, 0, 0, 0);
        }
        // C: row=dv=dvt*16+quad*4+r, col=query=l15
        if (is_pix) {
            const int q = qrow0 + w*16 + l15;
            float v[4];
            #pragma unroll
            for (int r = 0; r < 4; ++r) {
                const int dv = dvt*16 + quad*4 + r;
                v[r] = fmaxf(acc[r] * (bn_pret[h*32 + dv]*INVC) + bn_pret[256 + h*32 + dv], 0.f);
            }
            unsigned long long pk = (unsigned long long)f2bf2(v[0], v[1])
                                  | ((unsigned long long)f2bf2(v[2], v[3]) << 32);
            *(unsigned long long*)&pret[((size_t)q << 8) + h*32 + dvt*16 + quad*4] = pk;
        } else {
            const int bh = b*8 + h;
            const int q = qh*64 + w*16 + l15;
            float4 st = make_float4(acc[0], acc[1], acc[2], acc[3]);
            *(float4*)&part_acc[((size_t)(bh*NCHUNK + c)*128 + q)*32 + dvt*16 + quad*4] = st;
        }
    }
    if (!is_pix && quad == 0) {
        const int bh = b*8 + h;
        const int q = qh*64 + w*16 + l15;
        size_t o = ((size_t)(bh*NCHUNK + c)*128 + q) * 2;
        float2 ml = make_float2(mstat, lstat);
        *(float2*)&part_ml[o] = ml;
    }
}

// ---------------------------------------------------------------------------
// L5: pix3 gemm (256 blocks) + [flash-combine + mem3 -> moB] (64 blocks)
// ---------------------------------------------------------------------------
__global__ __launch_bounds__(256) void k_pix3_combmem3(
    const unsigned short* __restrict__ pretB, const unsigned short* __restrict__ Wt5,
    const float* __restrict__ bn_pix3, const float* __restrict__ pixel_input,
    float* __restrict__ out_pix,
    const float* __restrict__ part_acc, const float* __restrict__ part_ml,
    const float* __restrict__ bn_ret,
    const unsigned short* __restrict__ Wt4, const float* __restrict__ bn3,
    const float* __restrict__ memory_input,
    unsigned short* __restrict__ moB)
{
    __shared__ unsigned short As[8 * 512];
    __shared__ unsigned short Bs[8 * 512];
    const int bx = blockIdx.x;
    if (bx < 256) {
        gemm_body(pretB, Wt5, bn_pix3, pixel_input, out_pix, 256, 128,
                  bx * 128, 0, As, Bs);
        return;
    }
    unsigned short* mretA = As;
    const int t = threadIdx.x;
    const int lane = t & 63, w = t >> 6;
    const int l15 = lane & 15, quad = lane >> 4;
    const int g0 = (bx - 256) * 16;
    const int b = g0 >> 7;
    const int nbase = g0 & 127;

    {
        const int row = t >> 4;
        const int c0 = (t & 15) * 16;
        const int h = c0 >> 5;
        const int n = nbase + row;
        const int bh = b*8 + h;
        float m_g = -1e30f;
        for (int s = 0; s < NCHUNK; ++s)
            m_g = fmaxf(m_g, part_ml[((size_t)(bh*NCHUNK + s)*128 + n)*2]);
        float l_g = 0.f;
        float og[16];
        #pragma unroll
        for (int e = 0; e < 16; ++e) og[e] = 0.f;
        for (int s = 0; s < NCHUNK; ++s) {
            size_t o = ((size_t)(bh*NCHUNK + s)*128 + n)*2;
            float wgt = __expf(part_ml[o] - m_g);
            l_g += part_ml[o+1] * wgt;
            const float* pa = part_acc + ((size_t)(bh*NCHUNK + s)*128 + n)*32 + (c0 & 31);
            #pragma unroll
            for (int e = 0; e < 16; e += 4) {
                float4 v = *(const float4*)(pa + e);
                og[e]   += v.x*wgt; og[e+1] += v.y*wgt;
                og[e+2] += v.z*wgt; og[e+3] += v.w*wgt;
            }
        }
        float invl = __builtin_amdgcn_rcpf(l_g);
        #pragma unroll
        for (int e = 0; e < 16; ++e) {
            int col = c0 + e;
            int dv = col & 31;
            float v = og[e]*invl*(bn_ret[h*32+dv]*INVC) + bn_ret[256 + h*32 + dv];
            mretA[fidx(row, col)] = f2bf(fmaxf(v, 0.f));
        }
    }
    __syncthreads();

    #pragma unroll
    for (int i = 0; i < 2; ++i) {
        const int n0 = (w*2 + i) * 16;
        floatx4 acc = {0.f,0.f,0.f,0.f};
        #pragma unroll
        for (int kc = 0; kc < 8; ++kc) {
            short8 a = *(const short8*)&mretA[kc*512 + lane*8];
            short8 bfr = *(const short8*)&Wt4[(size_t)(n0 + l15)*256 + kc*32 + quad*8];
            acc = __builtin_amdgcn_mfma_f32_16x16x32_bf16(a, bfr, acc, 0, 0, 0);
        }
        const int col = n0 + l15;
        const float g = bn3[col]*INVC, be = bn3[128 + col];
        #pragma unroll
        for (int r = 0; r < 4; ++r) {
            const int row = quad*4 + r;
            float v = acc[r]*g + be + memory_input[(size_t)(g0 + row)*128 + col];
            moB[(size_t)(g0 + row)*128 + col] = f2bf(fmaxf(v, 0.f));
        }
    }
}

// ---------------------------------------------------------------------------
// L6: ffn1+ffn2, 64 blocks x 1024 threads (16 waves)
// ---------------------------------------------------------------------------
__global__ __launch_bounds__(1024) void k_ffn(
    const unsigned short* __restrict__ moB,
    const unsigned short* __restrict__ Wt6, const float* __restrict__ bnf1,
    const unsigned short* __restrict__ Wt7, const float* __restrict__ bnf2,
    float* __restrict__ out_mem)
{
    __shared__ unsigned short moA[4*512];
    __shared__ unsigned short fA[64*512];
    __shared__ floatx4 red[2][8][64];
    const int t = threadIdx.x;
    const int lane = t & 63, w = t >> 6;
    const int l15 = lane & 15, quad = lane >> 4;
    const int g0 = blockIdx.x * 16;

    if (t < 256) {
        const int row = t >> 4;
        const int c0 = (t & 15) * 8;
        uint4 v = *(const uint4*)(moB + (size_t)(g0 + row)*128 + c0);
        unsigned short ev[8] = {
            (unsigned short)(v.x & 0xffffu), (unsigned short)(v.x >> 16),
            (unsigned short)(v.y & 0xffffu), (unsigned short)(v.y >> 16),
            (unsigned short)(v.z & 0xffffu), (unsigned short)(v.z >> 16),
            (unsigned short)(v.w & 0xffffu), (unsigned short)(v.w >> 16)};
        #pragma unroll
        for (int e = 0; e < 8; ++e) moA[fidx(row, c0+e)] = ev[e];
    }
    __syncthreads();

    #pragma unroll
    for (int i = 0; i < 8; ++i) {
        const int n0 = (w*8 + i) * 16;
        floatx4 acc = {0.f,0.f,0.f,0.f};
        #pragma unroll
        for (int kc = 0; kc < 4; ++kc) {
            short8 a = *(const short8*)&moA[kc*512 + lane*8];
            short8 bfr = *(const short8*)&Wt6[(size_t)(n0 + l15)*128 + kc*32 + quad*8];
            acc = __builtin_amdgcn_mfma_f32_16x16x32_bf16(a, bfr, acc, 0, 0, 0);
        }
        const int col = n0 + l15;
        const float g = bnf1[col]*INVC, be = bnf1[2048 + col];
        #pragma unroll
        for (int r = 0; r < 4; ++r)
            fA[fidx(quad*4 + r, col)] = f2bf(fmaxf(acc[r]*g + be, 0.f));
    }
    __syncthreads();

    {
        const int ntile = w & 7, khalf = w >> 3;
        const int n0 = ntile * 16;
        floatx4 acc = {0.f,0.f,0.f,0.f};
        #pragma unroll 8
        for (int kc = 0; kc < 32; ++kc) {
            const int kcu = khalf*32 + kc;
            short8 a = *(const short8*)&fA[kcu*512 + lane*8];
            short8 bfr = *(const short8*)&Wt7[(size_t)(n0 + l15)*2048 + kcu*32 + quad*8];
            acc = __builtin_amdgcn_mfma_f32_16x16x32_bf16(a, bfr, acc, 0, 0, 0);
        }
        red[khalf][ntile][lane] = acc;
    }
    __syncthreads();
    if (w < 8) {
        const int n0 = w * 16;
        floatx4 s0 = red[0][w][lane];
        floatx4 s1 = red[1][w][lane];
        const int col = n0 + l15;
        const float g = bnf2[col]*INVC, be = bnf2[128 + col];
        #pragma unroll
        for (int r = 0; r < 4; ++r) {
            const int row = quad*4 + r;
            float resid = bf2f(moA[fidx(row, col)]);
            float v = fmaxf((s0[r] + s1[r])*g + be + resid, 0.f);
            out_mem[(size_t)(g0 + row)*128 + col] = v;
        }
    }
}

// ---------------------------------------------------------------------------
extern "C" void kernel_launch(void* const* d_in, const int* in_sizes, int n_in,
                              void* d_out, int out_size, void* d_ws, size_t ws_size,
                              hipStream_t stream) {
    const float* pixel_input  = (const float*)d_in[0];
    const float* memory_input = (const float*)d_in[1];
    const float* W_mem1    = (const float*)d_in[2];
    const float* bn_mem1   = (const float*)d_in[3];
    const float* W_pix1    = (const float*)d_in[4];
    const float* bn_pix1   = (const float*)d_in[5];
    const float* W_mem_qkv = (const float*)d_in[6];
    const float* bn_mem_qkv= (const float*)d_in[7];
    const float* W_pix_qkv = (const float*)d_in[8];
    const float* bn_pix_qkv= (const float*)d_in[9];
    const float* bn_mem_sim= (const float*)d_in[10];
    const float* bn_mem_ret= (const float*)d_in[11];
    const float* bn_pix_sim= (const float*)d_in[12];
    const float* bn_pix_ret= (const float*)d_in[13];
    const float* W_mem3    = (const float*)d_in[14];
    const float* bn_mem3   = (const float*)d_in[15];
    const float* W_pix3    = (const float*)d_in[16];
    const float* bn_pix3   = (const float*)d_in[17];
    const float* W_ffn1    = (const float*)d_in[18];
    const float* bn_ffn1   = (const float*)d_in[19];
    const float* W_ffn2    = (const float*)d_in[20];
    const float* bn_ffn2   = (const float*)d_in[21];

    char* ws = (char*)d_ws;
    size_t off = 0;
    auto alloc = [&](size_t bytes) -> void* {
        void* p = ws + off; off += (bytes + 255) & ~(size_t)255; return p;
    };
    unsigned short* pixB  = (unsigned short*)alloc((size_t)32768*128*2);
    unsigned short* Wt0   = (unsigned short*)alloc((size_t)256*128*2);
    unsigned short* Wt1   = (unsigned short*)alloc((size_t)256*128*2);
    unsigned short* Wt2   = (unsigned short*)alloc((size_t)512*256*2);
    unsigned short* Wt3   = (unsigned short*)alloc((size_t)512*256*2);
    unsigned short* Wt4   = (unsigned short*)alloc((size_t)128*256*2);
    unsigned short* Wt5   = (unsigned short*)alloc((size_t)128*256*2);
    unsigned short* Wt6   = (unsigned short*)alloc((size_t)2048*128*2);
    unsigned short* Wt7   = (unsigned short*)alloc((size_t)128*2048*2);
    unsigned short* mqkvB = (unsigned short*)alloc((size_t)1024*512*2);
    unsigned short* pqkvB = (unsigned short*)alloc((size_t)32768*512*2);
    float* part_acc = (float*)alloc((size_t)64*NCHUNK*128*32*4);
    float* part_ml  = (float*)alloc((size_t)64*NCHUNK*128*2*4);
    unsigned short* pretB = (unsigned short*)alloc((size_t)32768*256*2);
    unsigned short* moB   = (unsigned short*)alloc((size_t)1024*128*2);

    float* out_pix = (float*)d_out;
    float* out_mem = (float*)d_out + (size_t)8*4096*128;

    PrepPtrs P;
    P.src_pix = pixel_input;
    P.dst_pix = pixB;
    P.W[0]=W_mem1; P.W[1]=W_pix1; P.W[2]=W_mem_qkv; P.W[3]=W_pix_qkv;
    P.W[4]=W_mem3; P.W[5]=W_pix3; P.W[6]=W_ffn1;    P.W[7]=W_ffn2;
    P.Wt[0]=Wt0; P.Wt[1]=Wt1; P.Wt[2]=Wt2; P.Wt[3]=Wt3;
    P.Wt[4]=Wt4; P.Wt[5]=Wt5; P.Wt[6]=Wt6; P.Wt[7]=Wt7;

    dim3 blk(256);
    // L1: casts + weight transposes
    prep_kernel<<<4992, blk, 0, stream>>>(P);
    // L2: fused pix1+pqkv + mem front (cast+mem1+mqkv)
    k_qkv<<<320, blk, 0, stream>>>(pixB, Wt1, bn_pix1, Wt3, bn_pix_qkv, pqkvB,
        memory_input, Wt0, bn_mem1, Wt2, bn_mem_qkv, mqkvB);
    // L3: unified attention (pix sigmoid 4096 blocks + mem chunks 4224 blocks)
    k_attn<<<4096 + 128*NCHUNK, blk, 0, stream>>>(pqkvB, mqkvB,
        bn_pix_sim, bn_pix_ret, pretB, bn_mem_sim, part_acc, part_ml);
    // L4: pix3 gemm (+resid,relu -> out_pix) + combine+mem3 -> moB
    k_pix3_combmem3<<<320, blk, 0, stream>>>(pretB, Wt5, bn_pix3, pixel_input, out_pix,
        part_acc, part_ml, bn_mem_ret, Wt4, bn_mem3, memory_input, moB);
    // L5: ffn1+ffn2 -> out_mem
    k_ffn<<<64, dim3(1024), 0, stream>>>(moB, Wt6, bn_ffn1, Wt7, bn_ffn2, out_mem);
}